// Round 1
// baseline (297.827 us; speedup 1.0000x reference)
//
#include <hip/hip_runtime.h>
#include <hip/hip_bf16.h>

#define B_ 4
#define C_ 512
#define L_ 2048
#define H_ 8
#define D_ 64
#define EPS_ 1e-5f

using short8 = __attribute__((ext_vector_type(8))) short;
using f32x4  = __attribute__((ext_vector_type(4))) float;

static __device__ __forceinline__ short f2bf(float f) {
  __hip_bfloat16 h = __float2bfloat16(f);
  return __builtin_bit_cast(short, h);
}
static __device__ __forceinline__ float bf2f(short s) {
  return __bfloat162float(__builtin_bit_cast(__hip_bfloat16, s));
}

// ---------------- Kernel 1: convert weights fp32 [in][out] -> bf16 [out][in] ----
__global__ __launch_bounds__(256) void k_convert_w(
    const float* __restrict__ Wq, const float* __restrict__ Wk,
    const float* __restrict__ Wv, const float* __restrict__ Wo,
    short* __restrict__ Wt) {
  int idx = blockIdx.x * 256 + threadIdx.x;     // 4 * 512 * 512
  int m = idx >> 18;
  int r = idx & 262143;
  int n = r >> 9;
  int k = r & 511;
  const float* W = (m == 0) ? Wq : (m == 1) ? Wk : (m == 2) ? Wv : Wo;
  Wt[idx] = f2bf(W[k * C_ + n]);   // Wt[m][n][k] = W[k][n]
}

// ---------------- Kernel 2: transpose + pos + LayerNorm -> bf16 (B,L,C) --------
__global__ __launch_bounds__(256) void k_prep(
    const float* __restrict__ query, const float* __restrict__ kv,
    const float* __restrict__ pos,
    const float* __restrict__ qg, const float* __restrict__ qb,
    const float* __restrict__ kg, const float* __restrict__ kb,
    short* __restrict__ qn, short* __restrict__ kvn) {
  int l0 = blockIdx.x * 16;
  int b  = blockIdx.y;
  int z  = blockIdx.z;
  const float* src = z ? kv : query;
  const float* g   = z ? kg : qg;
  const float* be  = z ? kb : qb;
  short* dst       = z ? kvn : qn;

  __shared__ float T[16][516];
  __shared__ float mu_s[16], rs_s[16];
  int t = threadIdx.x;

  // load src (B,C,L): coalesced over l
  for (int i = 0; i < 32; ++i) {
    int flat = i * 256 + t;
    int c = flat >> 4, ll = flat & 15;
    T[ll][c] = src[(size_t)(b * C_ + c) * L_ + l0 + ll];
  }
  __syncthreads();
  // add pos (1,MAX_LEN,C): coalesced over c
  for (int i = 0; i < 32; ++i) {
    int flat = i * 256 + t;
    int ll = flat >> 9, c = flat & 511;
    T[ll][c] += pos[(size_t)(l0 + ll) * C_ + c];
  }
  __syncthreads();
  // stats: 16 threads per row
  {
    int row = t >> 4, j = t & 15;
    float s1 = 0.f, s2 = 0.f;
    for (int c = j; c < C_; c += 16) { float v = T[row][c]; s1 += v; s2 += v * v; }
    for (int m = 1; m < 16; m <<= 1) {
      s1 += __shfl_xor(s1, m, 64);
      s2 += __shfl_xor(s2, m, 64);
    }
    if (j == 0) {
      float mu  = s1 * (1.0f / C_);
      float var = s2 * (1.0f / C_) - mu * mu;
      mu_s[row] = mu;
      rs_s[row] = rsqrtf(var + EPS_);
    }
  }
  __syncthreads();
  // normalize + write bf16 (B,L,C), coalesced over c
  for (int i = 0; i < 32; ++i) {
    int flat = i * 256 + t;
    int ll = flat >> 9, c = flat & 511;
    float v = (T[ll][c] - mu_s[ll]) * rs_s[ll] * g[c] + be[c];
    dst[(size_t)(b * L_ + l0 + ll) * C_ + c] = f2bf(v);
  }
}

// ---------------- Kernel 3: fused QKV projection GEMM ---------------------------
// Y(M=8192,N=512) = X(M,512) @ W^T-staged + bias. 128x128 tile, BK=32.
__global__ __launch_bounds__(256) void k_gemm_qkv(
    const short* __restrict__ qn, const short* __restrict__ kvn,
    const short* __restrict__ Wt,
    const float* __restrict__ bq, const float* __restrict__ bk, const float* __restrict__ bv,
    short* __restrict__ Qw, short* __restrict__ Kw, short* __restrict__ Vw) {
  int z = blockIdx.z;
  const short* X    = z ? kvn : qn;
  const short* W    = Wt + (size_t)z * C_ * C_;   // [n][k]
  const float* bias = (z == 0) ? bq : (z == 1) ? bk : bv;
  short* Y          = (z == 0) ? Qw : (z == 1) ? Kw : Vw;

  int m0 = blockIdx.x * 128, n0 = blockIdx.y * 128;
  __shared__ alignas(16) short As[128 * 40];
  __shared__ alignas(16) short Bs[128 * 40];
  int t = threadIdx.x, lane = t & 63, w = t >> 6;
  int wm = w & 1, wn = w >> 1;

  f32x4 zero4 = {0.f, 0.f, 0.f, 0.f};
  f32x4 acc[4][4];
  for (int i = 0; i < 4; ++i) for (int j = 0; j < 4; ++j) acc[i][j] = zero4;

  for (int k0 = 0; k0 < C_; k0 += 32) {
    __syncthreads();
    for (int j = 0; j < 2; ++j) {
      int flat = j * 2048 + t * 8;
      int row = flat >> 5, col = flat & 31;
      *(short8*)(As + row * 40 + col) = *(const short8*)(X + (size_t)(m0 + row) * C_ + k0 + col);
      *(short8*)(Bs + row * 40 + col) = *(const short8*)(W + (size_t)(n0 + row) * C_ + k0 + col);
    }
    __syncthreads();
    short8 a[4], bf[4];
    for (int i = 0; i < 4; ++i)
      a[i]  = *(const short8*)(As + (wm * 64 + i * 16 + (lane & 15)) * 40 + ((lane >> 4) << 3));
    for (int i = 0; i < 4; ++i)
      bf[i] = *(const short8*)(Bs + (wn * 64 + i * 16 + (lane & 15)) * 40 + ((lane >> 4) << 3));
    for (int i = 0; i < 4; ++i)
      for (int j = 0; j < 4; ++j)
        acc[i][j] = __builtin_amdgcn_mfma_f32_16x16x32_bf16(a[i], bf[j], acc[i][j], 0, 0, 0);
  }

  for (int i = 0; i < 4; ++i)
    for (int j = 0; j < 4; ++j) {
      int colg = n0 + wn * 64 + j * 16 + (lane & 15);
      float bia = bias[colg];
      for (int r = 0; r < 4; ++r) {
        int rowg = m0 + wm * 64 + i * 16 + (lane >> 4) * 4 + r;
        Y[(size_t)rowg * C_ + colg] = f2bf(acc[i][j][r] + bia);
      }
    }
}

// ---------------- Kernel 4: attention (no-max flash; clip makes exp safe) -------
__global__ __launch_bounds__(256) void k_attn(
    const short* __restrict__ Qw, const short* __restrict__ Kw,
    const short* __restrict__ Vw, short* __restrict__ Ow) {
  int l0 = blockIdx.x * 64;
  int h  = blockIdx.y;
  int b  = blockIdx.z;
  __shared__ alignas(16) short Kt[32 * 72];     // [lr][d]
  __shared__ alignas(16) short Vt[64 * 40];     // [d][lr]  (transposed)
  __shared__ alignas(16) short Pl[4][16 * 40];  // per-wave P tile [m][lr]
  int t = threadIdx.x, lane = t & 63, w = t >> 6;

  // Q A-fragments for this wave's 16-row strip (K=64 -> 2 chunks)
  short8 qa[2];
  {
    int row = b * L_ + l0 + w * 16 + (lane & 15);
    const short* qptr = Qw + ((size_t)row * H_ + h) * D_ + ((lane >> 4) << 3);
    qa[0] = *(const short8*)(qptr);
    qa[1] = *(const short8*)(qptr + 32);
  }

  f32x4 zero4 = {0.f, 0.f, 0.f, 0.f};
  f32x4 acc_o[4];
  for (int i = 0; i < 4; ++i) acc_o[i] = zero4;
  float l_acc[4] = {0.f, 0.f, 0.f, 0.f};

  for (int lr0 = 0; lr0 < L_; lr0 += 32) {
    __syncthreads();
    {
      int row = t >> 3, d = (t & 7) << 3;
      size_t g = ((size_t)(b * L_ + lr0 + row) * H_ + h) * D_ + d;
      short8 k8 = *(const short8*)(Kw + g);
      *(short8*)(Kt + row * 72 + d) = k8;
      short8 v8 = *(const short8*)(Vw + g);
      for (int j = 0; j < 8; ++j) Vt[(d + j) * 40 + row] = v8[j];
    }
    __syncthreads();

    f32x4 s[2] = {zero4, zero4};
    for (int nt = 0; nt < 2; ++nt)
      for (int kc = 0; kc < 2; ++kc) {
        short8 kbf = *(const short8*)(Kt + (nt * 16 + (lane & 15)) * 72 + kc * 32 + ((lane >> 4) << 3));
        s[nt] = __builtin_amdgcn_mfma_f32_16x16x32_bf16(qa[kc], kbf, s[nt], 0, 0, 0);
      }
    for (int nt = 0; nt < 2; ++nt)
      for (int r = 0; r < 4; ++r) {
        float sv = s[nt][r] * 0.125f;                 // / sqrt(64)
        sv = fminf(fmaxf(sv, -50.f), 50.f);           // clip
        float p = __expf(sv);
        l_acc[r] += p;
        Pl[w][((lane >> 4) * 4 + r) * 40 + nt * 16 + (lane & 15)] = f2bf(p);
      }
    __syncthreads();   // C-layout -> A-layout via LDS (intra-wave lane exchange)

    short8 pf = *(const short8*)(Pl[w] + (lane & 15) * 40 + ((lane >> 4) << 3));
    for (int dc = 0; dc < 4; ++dc) {
      short8 vf = *(const short8*)(Vt + (dc * 16 + (lane & 15)) * 40 + ((lane >> 4) << 3));
      acc_o[dc] = __builtin_amdgcn_mfma_f32_16x16x32_bf16(pf, vf, acc_o[dc], 0, 0, 0);
    }
  }

  // row sums: reduce across the 16-lane groups (rows are per-quad)
  for (int r = 0; r < 4; ++r) {
    for (int m = 1; m < 16; m <<= 1) l_acc[r] += __shfl_xor(l_acc[r], m, 64);
    l_acc[r] = 1.0f / l_acc[r];
  }
  for (int dc = 0; dc < 4; ++dc)
    for (int r = 0; r < 4; ++r) {
      int row = b * L_ + l0 + w * 16 + (lane >> 4) * 4 + r;
      Ow[((size_t)row * H_ + h) * D_ + dc * 16 + (lane & 15)] = f2bf(acc_o[dc][r] * l_acc[r]);
    }
}

// ---------------- Kernel 5: output projection + bias + residual + transpose ----
__global__ __launch_bounds__(256) void k_gemm_out(
    const short* __restrict__ Ow, const short* __restrict__ Wot,
    const float* __restrict__ bo, const short* __restrict__ qn,
    float* __restrict__ out) {
  int m0 = blockIdx.x * 128, n0 = blockIdx.y * 128;
  __shared__ alignas(16) short As[128 * 40];
  __shared__ alignas(16) short Bs[128 * 40];
  int t = threadIdx.x, lane = t & 63, w = t >> 6;
  int wm = w & 1, wn = w >> 1;

  f32x4 zero4 = {0.f, 0.f, 0.f, 0.f};
  f32x4 acc[4][4];
  for (int i = 0; i < 4; ++i) for (int j = 0; j < 4; ++j) acc[i][j] = zero4;

  for (int k0 = 0; k0 < C_; k0 += 32) {
    __syncthreads();
    for (int j = 0; j < 2; ++j) {
      int flat = j * 2048 + t * 8;
      int row = flat >> 5, col = flat & 31;
      *(short8*)(As + row * 40 + col) = *(const short8*)(Ow  + (size_t)(m0 + row) * C_ + k0 + col);
      *(short8*)(Bs + row * 40 + col) = *(const short8*)(Wot + (size_t)(n0 + row) * C_ + k0 + col);
    }
    __syncthreads();
    short8 a[4], bf[4];
    for (int i = 0; i < 4; ++i)
      a[i]  = *(const short8*)(As + (wm * 64 + i * 16 + (lane & 15)) * 40 + ((lane >> 4) << 3));
    for (int i = 0; i < 4; ++i)
      bf[i] = *(const short8*)(Bs + (wn * 64 + i * 16 + (lane & 15)) * 40 + ((lane >> 4) << 3));
    for (int i = 0; i < 4; ++i)
      for (int j = 0; j < 4; ++j)
        acc[i][j] = __builtin_amdgcn_mfma_f32_16x16x32_bf16(a[i], bf[j], acc[i][j], 0, 0, 0);
  }

  for (int i = 0; i < 4; ++i)
    for (int j = 0; j < 4; ++j) {
      int colg = n0 + wn * 64 + j * 16 + (lane & 15);
      float bia = bo[colg];
      for (int r = 0; r < 4; ++r) {
        int rowg = m0 + wm * 64 + i * 16 + (lane >> 4) * 4 + r;
        float val = acc[i][j][r] + bia + bf2f(qn[(size_t)rowg * C_ + colg]);
        int bb = rowg >> 11, l = rowg & (L_ - 1);
        out[((size_t)bb * C_ + colg) * L_ + l] = val;   // (B, C, L)
      }
    }
}

extern "C" void kernel_launch(void* const* d_in, const int* in_sizes, int n_in,
                              void* d_out, int out_size, void* d_ws, size_t ws_size,
                              hipStream_t stream) {
  const float* query     = (const float*)d_in[0];
  const float* key_value = (const float*)d_in[1];
  const float* pos       = (const float*)d_in[2];
  const float* qg        = (const float*)d_in[3];
  const float* qb        = (const float*)d_in[4];
  const float* kg        = (const float*)d_in[5];
  const float* kb        = (const float*)d_in[6];
  const float* Wq        = (const float*)d_in[7];
  const float* bq        = (const float*)d_in[8];
  const float* Wk        = (const float*)d_in[9];
  const float* bk        = (const float*)d_in[10];
  const float* Wv        = (const float*)d_in[11];
  const float* bv        = (const float*)d_in[12];
  const float* Wo        = (const float*)d_in[13];
  const float* bo        = (const float*)d_in[14];
  float* out = (float*)d_out;

  char* ws = (char*)d_ws;
  const size_t SZ = (size_t)B_ * L_ * C_ * 2;   // 8 MB per bf16 (B,L,C) buffer
  short* qn  = (short*)(ws + 0 * SZ);
  short* kvn = (short*)(ws + 1 * SZ);
  short* Qw  = (short*)(ws + 2 * SZ);
  short* Kw  = (short*)(ws + 3 * SZ);
  short* Vw  = (short*)(ws + 4 * SZ);
  short* Ow  = (short*)(ws + 5 * SZ);
  short* Wt  = (short*)(ws + 6 * SZ);           // 4 x 512x512 bf16 = 2 MB

  k_convert_w<<<(4 * C_ * C_) / 256, 256, 0, stream>>>(Wq, Wk, Wv, Wo, Wt);
  k_prep<<<dim3(L_ / 16, B_, 2), 256, 0, stream>>>(query, key_value, pos, qg, qb, kg, kb, qn, kvn);
  k_gemm_qkv<<<dim3(8192 / 128, C_ / 128, 3), 256, 0, stream>>>(qn, kvn, Wt, bq, bk, bv, Qw, Kw, Vw);
  k_attn<<<dim3(L_ / 64, H_, B_), 256, 0, stream>>>(Qw, Kw, Vw, Ow);
  k_gemm_out<<<dim3(8192 / 128, C_ / 128, 1), 256, 0, stream>>>(Ow, Wt + (size_t)3 * C_ * C_, bo, qn, out);
}

// Round 2
// 235.056 us; speedup vs baseline: 1.2670x; 1.2670x over previous
//
#include <hip/hip_runtime.h>
#include <hip/hip_bf16.h>

#define B_ 4
#define C_ 512
#define L_ 2048
#define H_ 8
#define D_ 64
#define EPS_ 1e-5f

using short8 = __attribute__((ext_vector_type(8))) short;
using s4v    = __attribute__((ext_vector_type(4))) short;
using f32x4  = __attribute__((ext_vector_type(4))) float;

static __device__ __forceinline__ short f2bf(float f) {
  __hip_bfloat16 h = __float2bfloat16(f);
  return __builtin_bit_cast(short, h);
}
static __device__ __forceinline__ float bf2f(short s) {
  return __bfloat162float(__builtin_bit_cast(__hip_bfloat16, s));
}

// ---------------- Kernel 1: convert weights fp32 [in][out] -> bf16 [out][in] ----
// LDS 32x32 tile transpose: both global sides coalesced.
__global__ __launch_bounds__(256) void k_convert_w(
    const float* __restrict__ Wq, const float* __restrict__ Wk,
    const float* __restrict__ Wv, const float* __restrict__ Wo,
    short* __restrict__ Wt) {
  int m = blockIdx.x, k0 = blockIdx.y * 32, n0 = blockIdx.z * 32;
  const float* W = (m == 0) ? Wq : (m == 1) ? Wk : (m == 2) ? Wv : Wo;
  __shared__ float T[32][33];
  int t = threadIdx.x;
  {
    int kl = t >> 3, n4 = (t & 7) * 4;
    float4 v = *(const float4*)(W + (size_t)(k0 + kl) * C_ + n0 + n4);
    T[kl][n4] = v.x; T[kl][n4 + 1] = v.y; T[kl][n4 + 2] = v.z; T[kl][n4 + 3] = v.w;
  }
  __syncthreads();
  {
    int nl = t >> 3, k4 = (t & 7) * 4;
    s4v o;
#pragma unroll
    for (int j = 0; j < 4; ++j) o[j] = f2bf(T[k4 + j][nl]);
    *(s4v*)(Wt + (size_t)(m * C_ + n0 + nl) * C_ + k0 + k4) = o;   // Wt[m][n][k]
  }
}

// ---------------- Kernel 2: transpose + pos + LayerNorm -> bf16 (B,L,C) --------
__global__ __launch_bounds__(256) void k_prep(
    const float* __restrict__ query, const float* __restrict__ kv,
    const float* __restrict__ pos,
    const float* __restrict__ qg, const float* __restrict__ qb,
    const float* __restrict__ kg, const float* __restrict__ kb,
    short* __restrict__ qn, short* __restrict__ kvn) {
  int l0 = blockIdx.x * 16;
  int b  = blockIdx.y;
  int z  = blockIdx.z;
  const float* src = z ? kv : query;
  const float* g   = z ? kg : qg;
  const float* be  = z ? kb : qb;
  short* dst       = z ? kvn : qn;

  __shared__ float T[16][516];
  __shared__ float mu_s[16], rs_s[16];
  int t = threadIdx.x;

  for (int i = 0; i < 32; ++i) {
    int flat = i * 256 + t;
    int c = flat >> 4, ll = flat & 15;
    T[ll][c] = src[(size_t)(b * C_ + c) * L_ + l0 + ll];
  }
  __syncthreads();
  for (int i = 0; i < 32; ++i) {
    int flat = i * 256 + t;
    int ll = flat >> 9, c = flat & 511;
    T[ll][c] += pos[(size_t)(l0 + ll) * C_ + c];
  }
  __syncthreads();
  {
    int row = t >> 4, j = t & 15;
    float s1 = 0.f, s2 = 0.f;
    for (int c = j; c < C_; c += 16) { float v = T[row][c]; s1 += v; s2 += v * v; }
    for (int m = 1; m < 16; m <<= 1) {
      s1 += __shfl_xor(s1, m, 64);
      s2 += __shfl_xor(s2, m, 64);
    }
    if (j == 0) {
      float mu  = s1 * (1.0f / C_);
      float var = s2 * (1.0f / C_) - mu * mu;
      mu_s[row] = mu;
      rs_s[row] = rsqrtf(var + EPS_);
    }
  }
  __syncthreads();
  for (int i = 0; i < 32; ++i) {
    int flat = i * 256 + t;
    int ll = flat >> 9, c = flat & 511;
    float v = (T[ll][c] - mu_s[ll]) * rs_s[ll] * g[c] + be[c];
    dst[(size_t)(b * L_ + l0 + ll) * C_ + c] = f2bf(v);
  }
}

// ---------------- Kernel 3: fused QKV projection GEMM ---------------------------
__global__ __launch_bounds__(256) void k_gemm_qkv(
    const short* __restrict__ qn, const short* __restrict__ kvn,
    const short* __restrict__ Wt,
    const float* __restrict__ bq, const float* __restrict__ bk, const float* __restrict__ bv,
    short* __restrict__ Qw, short* __restrict__ Kw, short* __restrict__ Vw) {
  int z = blockIdx.z;
  const short* X    = z ? kvn : qn;
  const short* W    = Wt + (size_t)z * C_ * C_;
  const float* bias = (z == 0) ? bq : (z == 1) ? bk : bv;
  short* Y          = (z == 0) ? Qw : (z == 1) ? Kw : Vw;

  int m0 = blockIdx.x * 128, n0 = blockIdx.y * 128;
  __shared__ alignas(16) short As[128 * 40];
  __shared__ alignas(16) short Bs[128 * 40];
  int t = threadIdx.x, lane = t & 63, w = t >> 6;
  int wm = w & 1, wn = w >> 1;

  f32x4 zero4 = {0.f, 0.f, 0.f, 0.f};
  f32x4 acc[4][4];
  for (int i = 0; i < 4; ++i) for (int j = 0; j < 4; ++j) acc[i][j] = zero4;

  for (int k0 = 0; k0 < C_; k0 += 32) {
    __syncthreads();
    for (int j = 0; j < 2; ++j) {
      int flat = j * 2048 + t * 8;
      int row = flat >> 5, col = flat & 31;
      *(short8*)(As + row * 40 + col) = *(const short8*)(X + (size_t)(m0 + row) * C_ + k0 + col);
      *(short8*)(Bs + row * 40 + col) = *(const short8*)(W + (size_t)(n0 + row) * C_ + k0 + col);
    }
    __syncthreads();
    short8 a[4], bf[4];
    for (int i = 0; i < 4; ++i)
      a[i]  = *(const short8*)(As + (wm * 64 + i * 16 + (lane & 15)) * 40 + ((lane >> 4) << 3));
    for (int i = 0; i < 4; ++i)
      bf[i] = *(const short8*)(Bs + (wn * 64 + i * 16 + (lane & 15)) * 40 + ((lane >> 4) << 3));
    for (int i = 0; i < 4; ++i)
      for (int j = 0; j < 4; ++j)
        acc[i][j] = __builtin_amdgcn_mfma_f32_16x16x32_bf16(a[i], bf[j], acc[i][j], 0, 0, 0);
  }

  for (int i = 0; i < 4; ++i)
    for (int j = 0; j < 4; ++j) {
      int colg = n0 + wn * 64 + j * 16 + (lane & 15);
      float bia = bias[colg];
      for (int r = 0; r < 4; ++r) {
        int rowg = m0 + wm * 64 + i * 16 + (lane >> 4) * 4 + r;
        Y[(size_t)rowg * C_ + colg] = f2bf(acc[i][j][r] + bia);
      }
    }
}

// ---------------- Kernel 3b: V -> V^T per head: Vtg[b][h][d][l] ----------------
__global__ __launch_bounds__(256) void k_transpose_v(
    const short* __restrict__ Vw, short* __restrict__ Vtg) {
  int l0 = blockIdx.x * 64, h = blockIdx.y, b = blockIdx.z;
  __shared__ alignas(16) short T[64 * 64];   // XOR-swizzled 16B chunks
  int t = threadIdx.x;
#pragma unroll
  for (int p = 0; p < 2; ++p) {
    int flat = p * 256 + t;
    int l = flat >> 3, cc = flat & 7;
    int sw = (l & 7) ^ ((l >> 3) & 7);
    *(short8*)(T + l * 64 + ((cc ^ sw) << 3)) =
        *(const short8*)(Vw + ((size_t)(b * L_ + l0 + l) * H_ + h) * D_ + (cc << 3));
  }
  __syncthreads();
#pragma unroll
  for (int p = 0; p < 2; ++p) {
    int flat = p * 256 + t;
    int d = flat >> 3, l8 = (flat & 7) * 8;
    int sw_hi = (l8 >> 3) & 7;
    short8 o;
#pragma unroll
    for (int j = 0; j < 8; ++j) {
      int pc = (d >> 3) ^ j ^ sw_hi;
      o[j] = T[(l8 + j) * 64 + (pc << 3) + (d & 7)];
    }
    *(short8*)(Vtg + ((size_t)(b * H_ + h) * D_ + d) * L_ + l0 + l8) = o;
  }
}

// ---------------- Kernel 4: attention, S^T orientation, no scalar LDS ----------
// S^T = K.Q^T (C-layout row=lr, col=q); P^T packed -> per-wave LDS (q-major)
// -> read back as B-frag; O^T = V^T.P^T. One staging barrier pair per 64 K-rows.
#define LDK 72
#define LDV 72
#define LDP 72
__global__ __launch_bounds__(256) void k_attn(
    const short* __restrict__ Qw, const short* __restrict__ Kw,
    const short* __restrict__ Vtg, short* __restrict__ Ow) {
  int l0 = blockIdx.x * 128;
  int h  = blockIdx.y;
  int b  = blockIdx.z;
  __shared__ alignas(16) short Kt[64 * LDK];
  __shared__ alignas(16) short Vt[64 * LDV];
  __shared__ alignas(16) short Pw[4][2][16 * LDP];
  int t = threadIdx.x, lane = t & 63, w = t >> 6;
  int quad = lane >> 4, c = lane & 15;

  // Q fragments (B-operand: n=q, k=d): 2 strips x 2 k-chunks
  short8 qa[2][2];
#pragma unroll
  for (int s = 0; s < 2; ++s) {
    int qrow = b * L_ + l0 + w * 32 + s * 16 + c;
    const short* qp = Qw + ((size_t)qrow * H_ + h) * D_ + quad * 8;
    qa[s][0] = *(const short8*)(qp);
    qa[s][1] = *(const short8*)(qp + 32);
  }

  f32x4 zero4 = {0.f, 0.f, 0.f, 0.f};
  f32x4 acc[2][4];
#pragma unroll
  for (int s = 0; s < 2; ++s)
    for (int dt = 0; dt < 4; ++dt) acc[s][dt] = zero4;
  float lsum[2] = {0.f, 0.f};

  const short* Kbase = Kw + (size_t)(b * L_) * C_ + h * D_;
  const short* Vbase = Vtg + (size_t)(b * H_ + h) * D_ * L_;

  for (int lr0 = 0; lr0 < L_; lr0 += 64) {
    __syncthreads();
#pragma unroll
    for (int p = 0; p < 2; ++p) {
      int flat = p * 256 + t;
      int r = flat >> 3, c8 = (flat & 7) * 8;
      *(short8*)(Kt + r * LDK + c8) = *(const short8*)(Kbase + (size_t)(lr0 + r) * C_ + c8);
      *(short8*)(Vt + r * LDV + c8) = *(const short8*)(Vbase + (size_t)r * L_ + lr0 + c8);
    }
    __syncthreads();

    short8 kf[4][2], vf[4][2];
#pragma unroll
    for (int T = 0; T < 4; ++T) {
      kf[T][0] = *(const short8*)(Kt + (T * 16 + c) * LDK + quad * 8);
      kf[T][1] = *(const short8*)(Kt + (T * 16 + c) * LDK + 32 + quad * 8);
    }
#pragma unroll
    for (int dt = 0; dt < 4; ++dt) {
      vf[dt][0] = *(const short8*)(Vt + (dt * 16 + c) * LDV + quad * 8);
      vf[dt][1] = *(const short8*)(Vt + (dt * 16 + c) * LDV + 32 + quad * 8);
    }

#pragma unroll
    for (int s = 0; s < 2; ++s) {
      f32x4 st[4] = {zero4, zero4, zero4, zero4};
#pragma unroll
      for (int T = 0; T < 4; ++T) {
        st[T] = __builtin_amdgcn_mfma_f32_16x16x32_bf16(kf[T][0], qa[s][0], st[T], 0, 0, 0);
        st[T] = __builtin_amdgcn_mfma_f32_16x16x32_bf16(kf[T][1], qa[s][1], st[T], 0, 0, 0);
      }
      short* pb = &Pw[w][s][0];
#pragma unroll
      for (int T = 0; T < 4; ++T) {
        s4v pk;
#pragma unroll
        for (int r = 0; r < 4; ++r) {
          float sv = st[T][r] * 0.125f;
          sv = fminf(fmaxf(sv, -50.f), 50.f);
          float p = __expf(sv);
          lsum[s] += p;
          pk[r] = f2bf(p);
        }
        *(s4v*)(pb + c * LDP + T * 16 + quad * 4) = pk;   // P^T -> Pq[q][lr]
      }
#pragma unroll
      for (int hf = 0; hf < 2; ++hf) {
        short8 pf = *(const short8*)(pb + c * LDP + hf * 32 + quad * 8);
#pragma unroll
        for (int dt = 0; dt < 4; ++dt)
          acc[s][dt] = __builtin_amdgcn_mfma_f32_16x16x32_bf16(vf[dt][hf], pf, acc[s][dt], 0, 0, 0);
      }
    }
  }

#pragma unroll
  for (int s = 0; s < 2; ++s) {
    lsum[s] += __shfl_xor(lsum[s], 16, 64);
    lsum[s] += __shfl_xor(lsum[s], 32, 64);
    float inv = 1.0f / lsum[s];
    int qrow = b * L_ + l0 + w * 32 + s * 16 + c;
#pragma unroll
    for (int dt = 0; dt < 4; ++dt) {
      s4v o;
#pragma unroll
      for (int r = 0; r < 4; ++r) o[r] = f2bf(acc[s][dt][r] * inv);
      *(s4v*)(Ow + ((size_t)qrow * H_ + h) * D_ + dt * 16 + quad * 4) = o;
    }
  }
}

// ---------------- Kernel 5: output projection + bias + residual + transpose ----
__global__ __launch_bounds__(256) void k_gemm_out(
    const short* __restrict__ Ow, const short* __restrict__ Wot,
    const float* __restrict__ bo, const short* __restrict__ qn,
    float* __restrict__ out) {
  int m0 = blockIdx.x * 128, n0 = blockIdx.y * 128;
  __shared__ alignas(16) short As[128 * 40];
  __shared__ alignas(16) short Bs[128 * 40];
  int t = threadIdx.x, lane = t & 63, w = t >> 6;
  int wm = w & 1, wn = w >> 1;

  f32x4 zero4 = {0.f, 0.f, 0.f, 0.f};
  f32x4 acc[4][4];
  for (int i = 0; i < 4; ++i) for (int j = 0; j < 4; ++j) acc[i][j] = zero4;

  for (int k0 = 0; k0 < C_; k0 += 32) {
    __syncthreads();
    for (int j = 0; j < 2; ++j) {
      int flat = j * 2048 + t * 8;
      int row = flat >> 5, col = flat & 31;
      *(short8*)(As + row * 40 + col) = *(const short8*)(Ow  + (size_t)(m0 + row) * C_ + k0 + col);
      *(short8*)(Bs + row * 40 + col) = *(const short8*)(Wot + (size_t)(n0 + row) * C_ + k0 + col);
    }
    __syncthreads();
    short8 a[4], bf[4];
    for (int i = 0; i < 4; ++i)
      a[i]  = *(const short8*)(As + (wm * 64 + i * 16 + (lane & 15)) * 40 + ((lane >> 4) << 3));
    for (int i = 0; i < 4; ++i)
      bf[i] = *(const short8*)(Bs + (wn * 64 + i * 16 + (lane & 15)) * 40 + ((lane >> 4) << 3));
    for (int i = 0; i < 4; ++i)
      for (int j = 0; j < 4; ++j)
        acc[i][j] = __builtin_amdgcn_mfma_f32_16x16x32_bf16(a[i], bf[j], acc[i][j], 0, 0, 0);
  }

  for (int i = 0; i < 4; ++i)
    for (int j = 0; j < 4; ++j) {
      int colg = n0 + wn * 64 + j * 16 + (lane & 15);
      float bia = bo[colg];
      for (int r = 0; r < 4; ++r) {
        int rowg = m0 + wm * 64 + i * 16 + (lane >> 4) * 4 + r;
        float val = acc[i][j][r] + bia + bf2f(qn[(size_t)rowg * C_ + colg]);
        int bb = rowg >> 11, l = rowg & (L_ - 1);
        out[((size_t)bb * C_ + colg) * L_ + l] = val;   // (B, C, L)
      }
    }
}

extern "C" void kernel_launch(void* const* d_in, const int* in_sizes, int n_in,
                              void* d_out, int out_size, void* d_ws, size_t ws_size,
                              hipStream_t stream) {
  const float* query     = (const float*)d_in[0];
  const float* key_value = (const float*)d_in[1];
  const float* pos       = (const float*)d_in[2];
  const float* qg        = (const float*)d_in[3];
  const float* qb        = (const float*)d_in[4];
  const float* kg        = (const float*)d_in[5];
  const float* kb        = (const float*)d_in[6];
  const float* Wq        = (const float*)d_in[7];
  const float* bq        = (const float*)d_in[8];
  const float* Wk        = (const float*)d_in[9];
  const float* bk        = (const float*)d_in[10];
  const float* Wv        = (const float*)d_in[11];
  const float* bv        = (const float*)d_in[12];
  const float* Wo        = (const float*)d_in[13];
  const float* bo        = (const float*)d_in[14];
  float* out = (float*)d_out;

  char* ws = (char*)d_ws;
  const size_t SZ = (size_t)B_ * L_ * C_ * 2;   // 8 MB per bf16 (B,L,C) buffer
  short* qn  = (short*)(ws + 0 * SZ);
  short* kvn = (short*)(ws + 1 * SZ);
  short* Qw  = (short*)(ws + 2 * SZ);
  short* Kw  = (short*)(ws + 3 * SZ);
  short* Vw  = (short*)(ws + 4 * SZ);
  short* Ow  = (short*)(ws + 5 * SZ);
  short* Wt  = (short*)(ws + 6 * SZ);           // 4 x 512x512 bf16 = 2 MB
  short* Vtg = kvn;   // kvn dead after k_gemm_qkv; reuse for V^T [b][h][d][l]

  k_convert_w<<<dim3(4, 16, 16), 256, 0, stream>>>(Wq, Wk, Wv, Wo, Wt);
  k_prep<<<dim3(L_ / 16, B_, 2), 256, 0, stream>>>(query, key_value, pos, qg, qb, kg, kb, qn, kvn);
  k_gemm_qkv<<<dim3(8192 / 128, C_ / 128, 3), 256, 0, stream>>>(qn, kvn, Wt, bq, bk, bv, Qw, Kw, Vw);
  k_transpose_v<<<dim3(L_ / 64, H_, B_), 256, 0, stream>>>(Vw, Vtg);
  k_attn<<<dim3(L_ / 128, H_, B_), 256, 0, stream>>>(Qw, Kw, Vtg, Ow);
  k_gemm_out<<<dim3(8192 / 128, C_ / 128, 1), 256, 0, stream>>>(Ow, Wt + (size_t)3 * C_ * C_, bo, qn, out);
}